// Round 1
// baseline (166.874 us; speedup 1.0000x reference)
//
#include <hip/hip_runtime.h>
#include <hip/hip_bf16.h>
#include <math.h>

#define V      21841
#define TOPK   250
#define CAP    2048
#define NT     256
#define NWAVE  (NT / 64)

__device__ __forceinline__ float clipf(float v) {
    return fminf(fmaxf(v, -1e15f), 1e15f);
}
// order-preserving float->uint key (ascending uint == ascending float)
__device__ __forceinline__ unsigned int enc(float v) {
    unsigned int b = __float_as_uint(v);
    return (b & 0x80000000u) ? ~b : (b | 0x80000000u);
}
__device__ __forceinline__ float dec(unsigned int k) {
    unsigned int b = (k & 0x80000000u) ? (k & 0x7FFFFFFFu) : ~k;
    return __uint_as_float(b);
}

__global__ __launch_bounds__(NT) void lnclamp_kernel(const float* __restrict__ in,
                                                     float* __restrict__ out) {
    __shared__ unsigned int hist[256];
    __shared__ unsigned int cand[CAP];
    __shared__ int cand_cnt;
    __shared__ unsigned int sh_bin, sh_krem, sh_cnt;
    __shared__ double redS[NWAVE], redS2[NWAVE];
    __shared__ float sh_mean, sh_istd;

    const int row = blockIdx.x;
    const int tid = threadIdx.x;
    const float* rp = in + (size_t)row * V;
    float* op = out + (size_t)row * V;

    // 21841 % 4 == 1, so row start alignment cycles with row & 3
    const int first = (4 - (row & 3)) & 3;   // first 16B-aligned element index
    const int nvec = (V - first) >> 2;
    const int tail = first + (nvec << 2);
    const float4* vp = reinterpret_cast<const float4*>(rp + first);

    unsigned int prefix = 0, pmask = 0, krem = TOPK;
    bool compacted = false;
    int ncand = 0;
    double s = 0.0, s2 = 0.0;

    for (int level = 0; level < 4; ++level) {
        const int shift = 24 - 8 * level;
        __syncthreads();
        for (int b = tid; b < 256; b += NT) hist[b] = 0;
        __syncthreads();

        if (!compacted) {
            if (tid < first) {
                unsigned int k = enc(clipf(rp[tid]));
                if ((k & pmask) == prefix) atomicAdd(&hist[(k >> shift) & 255u], 1u);
            }
            for (int j = tid; j < nvec; j += NT) {
                float4 v = vp[j];
                float vv[4] = {v.x, v.y, v.z, v.w};
#pragma unroll
                for (int q = 0; q < 4; ++q) {
                    unsigned int k = enc(clipf(vv[q]));
                    if ((k & pmask) == prefix) atomicAdd(&hist[(k >> shift) & 255u], 1u);
                }
            }
            for (int i = tail + tid; i < V; i += NT) {
                unsigned int k = enc(clipf(rp[i]));
                if ((k & pmask) == prefix) atomicAdd(&hist[(k >> shift) & 255u], 1u);
            }
        } else {
            for (int i = tid; i < ncand; i += NT) {
                unsigned int k = cand[i];
                if ((k & pmask) == prefix) atomicAdd(&hist[(k >> shift) & 255u], 1u);
            }
        }
        __syncthreads();

        if (tid == 0) {
            unsigned int cum = 0;
            int b = 255;
            for (;; --b) {
                cum += hist[b];
                if (cum >= krem || b == 0) break;
            }
            sh_bin = (unsigned int)b;
            sh_krem = krem - (cum - hist[b]);   // still needed inside selected bin
            sh_cnt = hist[b];
            cand_cnt = 0;
        }
        __syncthreads();
        prefix |= sh_bin << shift;
        pmask |= 255u << shift;
        krem = sh_krem;
        const unsigned int m = sh_cnt;

        if (!compacted && m <= CAP) {
            // single fused scan: compact matching keys; sum strictly-greater values
            if (tid < first) {
                float v = clipf(rp[tid]);
                unsigned int k = enc(v), km = k & pmask;
                if (km == prefix) { int p = atomicAdd(&cand_cnt, 1); cand[p] = k; }
                else if (km > prefix) { double dv = v; s += dv; s2 += dv * dv; }
            }
            for (int j = tid; j < nvec; j += NT) {
                float4 v4 = vp[j];
                float vv[4] = {v4.x, v4.y, v4.z, v4.w};
#pragma unroll
                for (int q = 0; q < 4; ++q) {
                    float v = clipf(vv[q]);
                    unsigned int k = enc(v), km = k & pmask;
                    if (km == prefix) { int p = atomicAdd(&cand_cnt, 1); cand[p] = k; }
                    else if (km > prefix) { double dv = v; s += dv; s2 += dv * dv; }
                }
            }
            for (int i = tail + tid; i < V; i += NT) {
                float v = clipf(rp[i]);
                unsigned int k = enc(v), km = k & pmask;
                if (km == prefix) { int p = atomicAdd(&cand_cnt, 1); cand[p] = k; }
                else if (km > prefix) { double dv = v; s += dv; s2 += dv * dv; }
            }
            __syncthreads();
            ncand = cand_cnt;
            compacted = true;
        }
    }

    const unsigned int T = prefix;   // full 32-bit key of the K-th largest

    if (compacted) {
        for (int i = tid; i < ncand; i += NT) {
            unsigned int k = cand[i];
            if (k > T) { double dv = (double)dec(k); s += dv; s2 += dv * dv; }
        }
    } else {
        // fallback (never compacted): sum all strictly-greater from global
        if (tid < first) {
            float v = clipf(rp[tid]);
            if (enc(v) > T) { double dv = v; s += dv; s2 += dv * dv; }
        }
        for (int j = tid; j < nvec; j += NT) {
            float4 v4 = vp[j];
            float vv[4] = {v4.x, v4.y, v4.z, v4.w};
#pragma unroll
            for (int q = 0; q < 4; ++q) {
                float v = clipf(vv[q]);
                if (enc(v) > T) { double dv = v; s += dv; s2 += dv * dv; }
            }
        }
        for (int i = tail + tid; i < V; i += NT) {
            float v = clipf(rp[i]);
            if (enc(v) > T) { double dv = v; s += dv; s2 += dv * dv; }
        }
    }

    // block-reduce s, s2 (wave shuffle then cross-wave via LDS)
    for (int off = 32; off > 0; off >>= 1) {
        s  += __shfl_down(s, off);
        s2 += __shfl_down(s2, off);
    }
    const int wid = tid >> 6, lane = tid & 63;
    if (lane == 0) { redS[wid] = s; redS2[wid] = s2; }
    __syncthreads();
    if (tid == 0) {
        double S = 0.0, S2 = 0.0;
        for (int w = 0; w < NWAVE; ++w) { S += redS[w]; S2 += redS2[w]; }
        const double vT = (double)dec(T);
        S  += (double)krem * vT;
        S2 += (double)krem * vT * vT;
        const double mean = S / (double)TOPK;
        const double var  = (S2 - S * S / (double)TOPK) / (double)(TOPK - 1);
        const double istd = 1.0 / sqrt(var + 1e-8);
        sh_mean = (float)mean;
        sh_istd = (float)istd;
    }
    __syncthreads();
    const float mean = sh_mean, istd = sh_istd;

    // output pass: normed -> exact GELU(n-1) -> *0.4  (POWER=1 => identity)
    auto outf = [&](float v) -> float {
        float n = (v - mean) * istd - 1.0f;
        float g = 0.5f * n * (1.0f + erff(n * 0.70710678118654752f));
        return g * 0.4f;
    };
    if (tid < first) op[tid] = outf(clipf(rp[tid]));
    float4* ovp = reinterpret_cast<float4*>(op + first);
    for (int j = tid; j < nvec; j += NT) {
        float4 v4 = vp[j];
        float4 o;
        o.x = outf(clipf(v4.x));
        o.y = outf(clipf(v4.y));
        o.z = outf(clipf(v4.z));
        o.w = outf(clipf(v4.w));
        ovp[j] = o;
    }
    for (int i = tail + tid; i < V; i += NT) op[i] = outf(clipf(rp[i]));
}

extern "C" void kernel_launch(void* const* d_in, const int* in_sizes, int n_in,
                              void* d_out, int out_size, void* d_ws, size_t ws_size,
                              hipStream_t stream) {
    const float* in = (const float*)d_in[0];
    float* out = (float*)d_out;
    const int rows = out_size / V;   // 2048
    hipLaunchKernelGGL(lnclamp_kernel, dim3(rows), dim3(NT), 0, stream, in, out);
}